// Round 11
// baseline (1013.569 us; speedup 1.0000x reference)
//
#include <hip/hip_runtime.h>

#define N_NODES 50000
#define N_EDGES 640000
#define HID 128
#define N_LAYERS 4
#define TILE_E 128

typedef _Float16 f16x8 __attribute__((ext_vector_type(8)));
typedef float f32x16 __attribute__((ext_vector_type(16)));

__device__ __forceinline__ float silu_f(float x) {
    return x * __builtin_amdgcn_rcpf(1.0f + __expf(-x));
}

__device__ __forceinline__ f32x16 zero16() {
    f32x16 z;
#pragma unroll
    for (int i = 0; i < 16; ++i) z[i] = 0.f;
    return z;
}

// h[i,c] = sum_k nodes[i,k]*emb_w[k,c] + emb_b[c]
__global__ void k_embed(const float* __restrict__ nodes, const float* __restrict__ ew,
                        const float* __restrict__ eb, float* __restrict__ h) {
    int idx = blockIdx.x * 256 + threadIdx.x;
    if (idx >= N_NODES * HID) return;
    int i = idx >> 7, c = idx & 127;
    float n0 = nodes[i * 3 + 0], n1 = nodes[i * 3 + 1], n2 = nodes[i * 3 + 2];
    h[idx] = n0 * ew[c] + n1 * ew[HID + c] + n2 * ew[2 * HID + c] + eb[c];
}

// ---- counting sort of edges by row ----
__global__ void k_hist(const int* __restrict__ row, int* __restrict__ deg) {
    int e = blockIdx.x * 256 + threadIdx.x;
    if (e < N_EDGES) atomicAdd(&deg[row[e]], 1);
}

__global__ __launch_bounds__(1024) void k_scan(const int* __restrict__ deg, int* __restrict__ off) {
    __shared__ int partial[1024];
    const int t = threadIdx.x;
    const int chunk = (N_NODES + 1023) / 1024;
    const int base = t * chunk;
    int s = 0;
    for (int i = 0; i < chunk; ++i) {
        int idx = base + i;
        if (idx < N_NODES) s += deg[idx];
    }
    partial[t] = s;
    __syncthreads();
    for (int o = 1; o < 1024; o <<= 1) {
        int v = (t >= o) ? partial[t - o] : 0;
        __syncthreads();
        partial[t] += v;
        __syncthreads();
    }
    int run = (t == 0) ? 0 : partial[t - 1];
    for (int i = 0; i < chunk; ++i) {
        int idx = base + i;
        if (idx < N_NODES) {
            off[idx] = run;
            run += deg[idx];
        }
    }
}

__global__ void k_scatter(const int* __restrict__ row, const int* __restrict__ col,
                          const float* __restrict__ ea, int* __restrict__ off,
                          int* __restrict__ row_s, int* __restrict__ col_s,
                          float* __restrict__ ea_s) {
    int e = blockIdx.x * 256 + threadIdx.x;
    if (e >= N_EDGES) return;
    int r = row[e];
    int pos = atomicAdd(&off[r], 1);
    row_s[pos] = r;
    col_s[pos] = col[e];
    ea_s[pos] = ea[e];
}

// Pack W2[l] (128x128) into single-f16 B-frags for the edge kernel.
__global__ __launch_bounds__(256) void k_packW2(const float* __restrict__ W2all,
                                                _Float16* __restrict__ W2p) {
    const int layer = blockIdx.x;
    const float* W2 = W2all + (size_t)layer * 128 * 128;
    _Float16* out = W2p + (size_t)layer * 128 * 128;
    const int t = threadIdx.x;
    for (int fl = t; fl < 2048; fl += 256) {
        int blk = fl >> 6, lane = fl & 63;
        int cb = blk >> 3, kb = blk & 7;
        int colg = cb * 32 + (lane & 31);
        int kbase = kb * 16 + (lane >> 5) * 8;
        f16x8 v;
#pragma unroll
        for (int j = 0; j < 8; ++j)
            v[j] = (_Float16)W2[(size_t)(kbase + j) * 128 + colg];
        *(f16x8*)&out[(size_t)fl * 8] = v;
    }
}

// Pack node-MLP / decoder weights into hi/lo split-f16 B-frags.
__global__ __launch_bounds__(256) void k_packAll(
    const float* __restrict__ ew1, const float* __restrict__ nw1,
    const float* __restrict__ nw2, const float* __restrict__ dw1,
    _Float16* __restrict__ WpA, _Float16* __restrict__ WpB,
    _Float16* __restrict__ WpN1, _Float16* __restrict__ WpN2,
    _Float16* __restrict__ WpD1) {
    const int b = blockIdx.x;
    const float* W; _Float16* dst; int K16;
    if (b < 4)       { W = ew1 + (size_t)b * 257 * 128;              dst = WpA  + (size_t)b * 32768; K16 = 8; }
    else if (b < 8)  { int l = b - 4;  W = ew1 + (size_t)l * 257 * 128 + 128 * 128; dst = WpB + (size_t)l * 32768; K16 = 8; }
    else if (b < 12) { int l = b - 8;  W = nw1 + (size_t)l * 256 * 128; dst = WpN1 + (size_t)l * 65536; K16 = 16; }
    else if (b < 16) { int l = b - 12; W = nw2 + (size_t)l * 128 * 128; dst = WpN2 + (size_t)l * 32768; K16 = 8; }
    else             { W = dw1; dst = WpD1; K16 = 8; }
    for (int fl = threadIdx.x; fl < K16 * 256; fl += 256) {
        int lane = fl & 63, cb = (fl >> 6) & 3, ks = fl >> 8;
        int col = cb * 32 + (lane & 31);
        int kb = ks * 16 + (lane >> 5) * 8;
        f16x8 h8, l8;
#pragma unroll
        for (int j = 0; j < 8; ++j) {
            float wv = W[(size_t)(kb + j) * 128 + col];
            _Float16 hh = (_Float16)wv;
            h8[j] = hh;
            l8[j] = (_Float16)((wv - (float)hh) * 2048.0f);
        }
        *(f16x8*)&dst[((size_t)(0 * K16 + ks) * 4 + cb) * 512 + lane * 8] = h8;
        *(f16x8*)&dst[((size_t)(1 * K16 + ks) * 4 + cb) * 512 + lane * 8] = l8;
    }
}

__device__ __forceinline__ void split8(const float* xv, f16x8& xh, f16x8& xl) {
#pragma unroll
    for (int q = 0; q < 8; ++q) {
        _Float16 hh = (_Float16)xv[q];
        xh[q] = hh;
        xl[q] = (_Float16)((xv[q] - (float)hh) * 2048.0f);
    }
}

// Split-f16 MFMA GEMM (initial A/B dual from h0).
__global__ __launch_bounds__(512) void k_gemm3(
    const float* __restrict__ X1, const float* __restrict__ X2,
    const _Float16* __restrict__ Wp0, const float* __restrict__ bias0, float* __restrict__ out0,
    const _Float16* __restrict__ Wp1, const float* __restrict__ bias1, float* __restrict__ out1,
    int M, int K16, int do_silu) {
    const int t = threadIdx.x, w = t >> 6, l = t & 63;
    const int lane31 = l & 31, hi = l >> 5;
    const bool dual = (Wp1 != nullptr);
    int rb, cb0, sel;
    if (dual) { rb = w & 1; sel = w >> 2; cb0 = ((w >> 1) & 1) * 2; }
    else      { rb = w & 3; sel = 0;      cb0 = (w >> 2) * 2; }
    const int mtile = dual ? 64 : 128;
    const int m0 = blockIdx.x * mtile;
    const _Float16* Wp = sel ? Wp1 : Wp0;
    const float* bias = sel ? bias1 : bias0;
    float* out = sel ? out1 : out0;

    int rowg = m0 + rb * 32 + lane31;
    if (rowg >= M) rowg = M - 1;
    const int koff = hi * 8;

    f32x16 aH0 = zero16(), aH1 = zero16(), aL0 = zero16(), aL1 = zero16();
    const f16x8* Wv = (const f16x8*)Wp;
#pragma unroll 4
    for (int ks = 0; ks < K16; ++ks) {
        const float* Xp = (X2 != nullptr && ks >= 8) ? X2 : X1;
        const float* px = &Xp[(size_t)rowg * 128 + (ks & 7) * 16 + koff];
        float xv[8];
        *(float4*)&xv[0] = *(const float4*)px;
        *(float4*)&xv[4] = *(const float4*)(px + 4);
        f16x8 xh, xl;
        split8(xv, xh, xl);
        f16x8 bh0 = Wv[((size_t)ks * 4 + cb0) * 64 + l];
        f16x8 bh1 = Wv[((size_t)ks * 4 + cb0 + 1) * 64 + l];
        f16x8 bl0 = Wv[((size_t)(K16 + ks) * 4 + cb0) * 64 + l];
        f16x8 bl1 = Wv[((size_t)(K16 + ks) * 4 + cb0 + 1) * 64 + l];
        aH0 = __builtin_amdgcn_mfma_f32_32x32x16_f16(xh, bh0, aH0, 0, 0, 0);
        aH1 = __builtin_amdgcn_mfma_f32_32x32x16_f16(xh, bh1, aH1, 0, 0, 0);
        aL0 = __builtin_amdgcn_mfma_f32_32x32x16_f16(xh, bl0, aL0, 0, 0, 0);
        aL0 = __builtin_amdgcn_mfma_f32_32x32x16_f16(xl, bh0, aL0, 0, 0, 0);
        aL1 = __builtin_amdgcn_mfma_f32_32x32x16_f16(xh, bl1, aL1, 0, 0, 0);
        aL1 = __builtin_amdgcn_mfma_f32_32x32x16_f16(xl, bh1, aL1, 0, 0, 0);
    }
    const float inv = 1.0f / 2048.0f;
#pragma unroll
    for (int c = 0; c < 2; ++c) {
        int col = (cb0 + c) * 32 + lane31;
        float bv = bias ? bias[col] : 0.f;
        const f32x16& aH = c ? aH1 : aH0;
        const f32x16& aL = c ? aL1 : aL0;
#pragma unroll
        for (int r = 0; r < 16; ++r) {
            int gr = m0 + rb * 32 + (r & 3) + 8 * (r >> 2) + 4 * hi;
            if (gr < M) {
                float v = aH[r] + aL[r] * inv + bv;
                out[(size_t)gr * 128 + col] = do_silu ? silu_f(v) : v;
            }
        }
    }
}

// Fused per-layer node kernel: u=silu([h,agg]@nw1+b) -> h'=u@nw2+b (in-place
// over h) -> next layer's A/B dual GEMM, OR (final) decoder to out[N,3].
// NOTE: plain launch_bounds(512) — a second arg pins VGPR=64 on this
// toolchain and forces spills (measured R6/R7/R9).
__global__ __launch_bounds__(512) void k_node(
    float* __restrict__ h, const float* __restrict__ agg,
    const _Float16* __restrict__ Wn1, const float* __restrict__ nb1,
    const _Float16* __restrict__ Wn2, const float* __restrict__ nb2,
    const _Float16* __restrict__ WA, const float* __restrict__ ebA,
    const _Float16* __restrict__ WB,
    float* __restrict__ outA, float* __restrict__ outB,
    const _Float16* __restrict__ WD, const float* __restrict__ db1,
    const float* __restrict__ dw2, const float* __restrict__ db2,
    float* __restrict__ dec_out, int M, int final_mode) {
    __shared__ float u_lds[128 * 133];
    __shared__ float w2l[384];
    const int t = threadIdx.x, w = t >> 6, l = t & 63;
    const int lane31 = l & 31, hi = l >> 5;
    const int rb = w & 3, cb0 = (w >> 2) * 2;
    const int m0 = blockIdx.x * 128;
    const int koff = hi * 8;
    const float inv = 1.0f / 2048.0f;

    if (final_mode && t < 384) w2l[t] = dw2[t];

    int rowg = m0 + rb * 32 + lane31;
    if (rowg >= M) rowg = M - 1;

    // ---- stage N1: u = silu([h, agg] @ nw1 + nb1) -> u_lds ----
    {
        f32x16 aH0 = zero16(), aH1 = zero16(), aL0 = zero16(), aL1 = zero16();
        const f16x8* Wv = (const f16x8*)Wn1;
#pragma unroll 4
        for (int ks = 0; ks < 16; ++ks) {
            const float* Xp = (ks >= 8) ? agg : h;
            const float* px = &Xp[(size_t)rowg * 128 + (ks & 7) * 16 + koff];
            float xv[8];
            *(float4*)&xv[0] = *(const float4*)px;
            *(float4*)&xv[4] = *(const float4*)(px + 4);
            f16x8 xh, xl;
            split8(xv, xh, xl);
            f16x8 bh0 = Wv[((size_t)ks * 4 + cb0) * 64 + l];
            f16x8 bh1 = Wv[((size_t)ks * 4 + cb0 + 1) * 64 + l];
            f16x8 bl0 = Wv[((size_t)(16 + ks) * 4 + cb0) * 64 + l];
            f16x8 bl1 = Wv[((size_t)(16 + ks) * 4 + cb0 + 1) * 64 + l];
            aH0 = __builtin_amdgcn_mfma_f32_32x32x16_f16(xh, bh0, aH0, 0, 0, 0);
            aH1 = __builtin_amdgcn_mfma_f32_32x32x16_f16(xh, bh1, aH1, 0, 0, 0);
            aL0 = __builtin_amdgcn_mfma_f32_32x32x16_f16(xh, bl0, aL0, 0, 0, 0);
            aL0 = __builtin_amdgcn_mfma_f32_32x32x16_f16(xl, bh0, aL0, 0, 0, 0);
            aL1 = __builtin_amdgcn_mfma_f32_32x32x16_f16(xh, bl1, aL1, 0, 0, 0);
            aL1 = __builtin_amdgcn_mfma_f32_32x32x16_f16(xl, bh1, aL1, 0, 0, 0);
        }
#pragma unroll
        for (int c = 0; c < 2; ++c) {
            int col = (cb0 + c) * 32 + lane31;
            float bv = nb1[col];
            const f32x16& aH = c ? aH1 : aH0;
            const f32x16& aL = c ? aL1 : aL0;
#pragma unroll
            for (int r = 0; r < 16; ++r) {
                int lr = rb * 32 + (r & 3) + 8 * (r >> 2) + 4 * hi;
                u_lds[lr * 133 + col] = silu_f(aH[r] + aL[r] * inv + bv);
            }
        }
    }
    __syncthreads();

    // ---- stage N2: h' = u @ nw2 + nb2 -> u_lds (+ global h if !final) ----
    {
        f32x16 aH0 = zero16(), aH1 = zero16(), aL0 = zero16(), aL1 = zero16();
        const f16x8* Wv = (const f16x8*)Wn2;
#pragma unroll
        for (int ks = 0; ks < 8; ++ks) {
            float xv[8];
            const int base = (rb * 32 + lane31) * 133 + ks * 16 + koff;
#pragma unroll
            for (int q = 0; q < 8; ++q) xv[q] = u_lds[base + q];
            f16x8 xh, xl;
            split8(xv, xh, xl);
            f16x8 bh0 = Wv[((size_t)ks * 4 + cb0) * 64 + l];
            f16x8 bh1 = Wv[((size_t)ks * 4 + cb0 + 1) * 64 + l];
            f16x8 bl0 = Wv[((size_t)(8 + ks) * 4 + cb0) * 64 + l];
            f16x8 bl1 = Wv[((size_t)(8 + ks) * 4 + cb0 + 1) * 64 + l];
            aH0 = __builtin_amdgcn_mfma_f32_32x32x16_f16(xh, bh0, aH0, 0, 0, 0);
            aH1 = __builtin_amdgcn_mfma_f32_32x32x16_f16(xh, bh1, aH1, 0, 0, 0);
            aL0 = __builtin_amdgcn_mfma_f32_32x32x16_f16(xh, bl0, aL0, 0, 0, 0);
            aL0 = __builtin_amdgcn_mfma_f32_32x32x16_f16(xl, bh0, aL0, 0, 0, 0);
            aL1 = __builtin_amdgcn_mfma_f32_32x32x16_f16(xh, bl1, aL1, 0, 0, 0);
            aL1 = __builtin_amdgcn_mfma_f32_32x32x16_f16(xl, bh1, aL1, 0, 0, 0);
        }
        __syncthreads();   // all u_lds reads done before overwrite
#pragma unroll
        for (int c = 0; c < 2; ++c) {
            int col = (cb0 + c) * 32 + lane31;
            float bv = nb2[col];
            const f32x16& aH = c ? aH1 : aH0;
            const f32x16& aL = c ? aL1 : aL0;
#pragma unroll
            for (int r = 0; r < 16; ++r) {
                int lr = rb * 32 + (r & 3) + 8 * (r >> 2) + 4 * hi;
                float v = aH[r] + aL[r] * inv + bv;
                u_lds[lr * 133 + col] = v;
                int gr = m0 + lr;
                if (!final_mode && gr < M) h[(size_t)gr * 128 + col] = v;
            }
        }
    }
    __syncthreads();

    if (!final_mode) {
        // ---- stage 3: A = h'@W1a + eb1, B = h'@W1b (next layer) ----
#pragma unroll
        for (int pass = 0; pass < 2; ++pass) {
            const int sel = w >> 2, w2 = w & 3;
            const int cbp = w2 >> 1, cb0p = (cbp) * 2;
            const int rb3 = (w2 & 1) * 2 + pass;
            const _Float16* Wp = sel ? WB : WA;
            float* op = sel ? outB : outA;
            f32x16 aH0 = zero16(), aH1 = zero16(), aL0 = zero16(), aL1 = zero16();
            const f16x8* Wv = (const f16x8*)Wp;
#pragma unroll
            for (int ks = 0; ks < 8; ++ks) {
                float xv[8];
                const int base = (rb3 * 32 + lane31) * 133 + ks * 16 + koff;
#pragma unroll
                for (int q = 0; q < 8; ++q) xv[q] = u_lds[base + q];
                f16x8 xh, xl;
                split8(xv, xh, xl);
                f16x8 bh0 = Wv[((size_t)ks * 4 + cb0p) * 64 + l];
                f16x8 bh1 = Wv[((size_t)ks * 4 + cb0p + 1) * 64 + l];
                f16x8 bl0 = Wv[((size_t)(8 + ks) * 4 + cb0p) * 64 + l];
                f16x8 bl1 = Wv[((size_t)(8 + ks) * 4 + cb0p + 1) * 64 + l];
                aH0 = __builtin_amdgcn_mfma_f32_32x32x16_f16(xh, bh0, aH0, 0, 0, 0);
                aH1 = __builtin_amdgcn_mfma_f32_32x32x16_f16(xh, bh1, aH1, 0, 0, 0);
                aL0 = __builtin_amdgcn_mfma_f32_32x32x16_f16(xh, bl0, aL0, 0, 0, 0);
                aL0 = __builtin_amdgcn_mfma_f32_32x32x16_f16(xl, bh0, aL0, 0, 0, 0);
                aL1 = __builtin_amdgcn_mfma_f32_32x32x16_f16(xh, bl1, aL1, 0, 0, 0);
                aL1 = __builtin_amdgcn_mfma_f32_32x32x16_f16(xl, bh1, aL1, 0, 0, 0);
            }
#pragma unroll
            for (int c = 0; c < 2; ++c) {
                int col = (cb0p + c) * 32 + lane31;
                float bv = sel ? 0.f : ebA[col];
                const f32x16& aH = c ? aH1 : aH0;
                const f32x16& aL = c ? aL1 : aL0;
#pragma unroll
                for (int r = 0; r < 16; ++r) {
                    int gr = m0 + rb3 * 32 + (r & 3) + 8 * (r >> 2) + 4 * hi;
                    if (gr < M) op[(size_t)gr * 128 + col] = aH[r] + aL[r] * inv + bv;
                }
            }
        }
    } else {
        // ---- decoder: u2 = silu(h'@dw1+db1) -> u_lds; out = u2@dw2+db2 ----
        f32x16 aH0 = zero16(), aH1 = zero16(), aL0 = zero16(), aL1 = zero16();
        const f16x8* Wv = (const f16x8*)WD;
#pragma unroll
        for (int ks = 0; ks < 8; ++ks) {
            float xv[8];
            const int base = (rb * 32 + lane31) * 133 + ks * 16 + koff;
#pragma unroll
            for (int q = 0; q < 8; ++q) xv[q] = u_lds[base + q];
            f16x8 xh, xl;
            split8(xv, xh, xl);
            f16x8 bh0 = Wv[((size_t)ks * 4 + cb0) * 64 + l];
            f16x8 bh1 = Wv[((size_t)ks * 4 + cb0 + 1) * 64 + l];
            f16x8 bl0 = Wv[((size_t)(8 + ks) * 4 + cb0) * 64 + l];
            f16x8 bl1 = Wv[((size_t)(8 + ks) * 4 + cb0 + 1) * 64 + l];
            aH0 = __builtin_amdgcn_mfma_f32_32x32x16_f16(xh, bh0, aH0, 0, 0, 0);
            aH1 = __builtin_amdgcn_mfma_f32_32x32x16_f16(xh, bh1, aH1, 0, 0, 0);
            aL0 = __builtin_amdgcn_mfma_f32_32x32x16_f16(xh, bl0, aL0, 0, 0, 0);
            aL0 = __builtin_amdgcn_mfma_f32_32x32x16_f16(xl, bh0, aL0, 0, 0, 0);
            aL1 = __builtin_amdgcn_mfma_f32_32x32x16_f16(xh, bl1, aL1, 0, 0, 0);
            aL1 = __builtin_amdgcn_mfma_f32_32x32x16_f16(xl, bh1, aL1, 0, 0, 0);
        }
        __syncthreads();
#pragma unroll
        for (int c = 0; c < 2; ++c) {
            int col = (cb0 + c) * 32 + lane31;
            float bv = db1[col];
            const f32x16& aH = c ? aH1 : aH0;
            const f32x16& aL = c ? aL1 : aL0;
#pragma unroll
            for (int r = 0; r < 16; ++r) {
                int lr = rb * 32 + (r & 3) + 8 * (r >> 2) + 4 * hi;
                u_lds[lr * 133 + col] = silu_f(aH[r] + aL[r] * inv + bv);
            }
        }
        __syncthreads();
        if (t < 384) {
            int rowl = t & 127, j = t >> 7;
            int gm = m0 + rowl;
            if (gm < M) {
                float s = db2[j];
                for (int c = 0; c < 128; ++c)
                    s += u_lds[rowl * 133 + c] * w2l[c * 3 + j];
                dec_out[(size_t)gm * 3 + j] = s;
            }
        }
    }
}

#define EPI9(ACC, BV) { _Pragma("unroll") \
    for (int rr = 0; rr < 16; ++rr) ACC[rr] = silu_f(ACC[rr] + BV); }

#define SEGSUM9(ACC, CB) { \
    float p = 0.f; \
    _Pragma("unroll") \
    for (int rr = 0; rr < 16; ++rr) { \
        int erow = (rr & 3) + 8 * (rr >> 2) + 4 * hi; \
        p += (erow >= st && erow < en) ? ACC[rr] : 0.f; \
    } \
    p += __shfl_xor(p, 32); \
    if (hi == 0) atomicAdd(&agg[(size_t)rseg * 128 + (CB) * 32 + lane31], p); }

// Edge kernel v9 = edge4 minus the phase3/phase4 LDS round-trip.
// Wave w owns edge row-block (w&3) end-to-end: phase-1 loads its own edges'
// k-half (w>>2), so the wave holds its rows' r in-register; epilogue +
// segment-reduce happen in registers (ballot segments, predicated sums,
// shfl_xor(32) half-merge). 2 barriers/tile instead of 4; LDS = 64KB.
__global__ __launch_bounds__(512) void k_edge9(
    const float* __restrict__ A, const float* __restrict__ Bm,
    const float* __restrict__ w1last, const float* __restrict__ b2,
    const _Float16* __restrict__ W2p, const int* __restrict__ row_s,
    const int* __restrict__ col_s, const float* __restrict__ ea_s,
    float* __restrict__ agg) {
    __shared__ __align__(16) _Float16 W2s[16384];
    __shared__ __align__(16) _Float16 m1f[16384];   // A-frags only (32 KB)

    const int t = threadIdx.x;
    const int w = t >> 6, l = t & 63;
    const int lane31 = l & 31, hi = l >> 5;

    for (int i = t; i < 2048; i += 512)
        ((float4*)W2s)[i] = ((const float4*)W2p)[i];

    const int rb = w & 3;                 // edge row-block owned
    const int kh = w >> 2;                // k-half for phase-1 loads
    const int kbase0 = kh * 64 + hi * 8;
    const int cb0 = kh * 2, cb1 = cb0 + 1; // col-blocks for MFMA/reduce
    const float b20 = b2[cb0 * 32 + lane31];
    const float b21 = b2[cb1 * 32 + lane31];
    const int e_mine = rb * 32 + lane31;  // edge within tile (own rows!)

    const f16x8* m1v = (const f16x8*)m1f;
    const f16x8* w2v = (const f16x8*)W2s;

    const int n_tiles = N_EDGES / TILE_E;  // 5000
    const int stride = gridDim.x;

    int r_pf = 0; float ea_pf = 0.f;
    float bpf[32];

    auto issue_pf = [&](int tile) {
        int eg = tile * TILE_E + e_mine;
        r_pf = row_s[eg];
        int c = col_s[eg];
        ea_pf = ea_s[eg];
        const float* Bp = Bm + (size_t)c * 128;
#pragma unroll
        for (int j = 0; j < 4; ++j) {
            int k0 = kbase0 + j * 16;
            *(float4*)&bpf[j * 8] = *(const float4*)&Bp[k0];
            *(float4*)&bpf[j * 8 + 4] = *(const float4*)&Bp[k0 + 4];
        }
    };

    int tile = blockIdx.x;
    if (tile < n_tiles) issue_pf(tile);

    for (; tile < n_tiles; tile += stride) {
        __syncthreads();  // m1f free (prev MFMA reads done); W2s staged (iter 0)

        // ---- phase 1: m1 = silu(A[row]+B[col]+ea*w1l) -> f16 A-frags ----
        {
            const float eav = ea_pf;
            const float* Ap = A + (size_t)r_pf * 128;
#pragma unroll
            for (int j = 0; j < 4; ++j) {
                int k0 = kbase0 + j * 16;
                float av[8], wv_[8];
                *(float4*)&av[0] = *(const float4*)&Ap[k0];
                *(float4*)&av[4] = *(const float4*)&Ap[k0 + 4];
                *(float4*)&wv_[0] = *(const float4*)&w1last[k0];
                *(float4*)&wv_[4] = *(const float4*)&w1last[k0 + 4];
                f16x8 o;
#pragma unroll
                for (int q = 0; q < 8; ++q)
                    o[q] = (_Float16)silu_f(av[q] + bpf[j * 8 + q] + eav * wv_[q]);
                *(f16x8*)&m1f[(rb * 8 + (k0 >> 4)) * 512 + l * 8] = o;
            }
        }
        __syncthreads();  // frags ready

        const int r_cur = r_pf;  // this wave's rows (before prefetch clobbers)
        int nt = tile + stride;
        if (nt < n_tiles) issue_pf(nt);   // prefetch hides under MFMA

        // ---- phase 2: MFMA ----
        f32x16 acc0 = zero16(), acc1 = zero16();
#pragma unroll
        for (int kb = 0; kb < 8; ++kb) {
            f16x8 a = m1v[(rb * 8 + kb) * 64 + l];
            acc0 = __builtin_amdgcn_mfma_f32_32x32x16_f16(a, w2v[(cb0 * 8 + kb) * 64 + l], acc0, 0, 0, 0);
            acc1 = __builtin_amdgcn_mfma_f32_32x32x16_f16(a, w2v[(cb1 * 8 + kb) * 64 + l], acc1, 0, 0, 0);
        }

        // ---- phase 3: in-register epilogue + segment reduce + atomics ----
        EPI9(acc0, b20) EPI9(acc1, b21)
        {
            int prev = __shfl_up(r_cur, 1, 32);
            bool flag = (lane31 == 0) || (r_cur != prev);
            unsigned mask = (unsigned)__ballot(flag);   // halves identical
            int ns = __popc(mask);
            unsigned mrem = mask;
            for (int s = 0; s < ns; ++s) {
                int st = __ffs(mrem) - 1;
                unsigned mnext = mrem & (mrem - 1);
                int en = mnext ? (__ffs(mnext) - 1) : 32;
                mrem = mnext;
                int rseg = __shfl(r_cur, st, 32);
                SEGSUM9(acc0, cb0) SEGSUM9(acc1, cb1)
            }
        }
    }
}

extern "C" void kernel_launch(void* const* d_in, const int* in_sizes, int n_in,
                              void* d_out, int out_size, void* d_ws, size_t ws_size,
                              hipStream_t stream) {
    const float* nodes = (const float*)d_in[0];
    const int* edges = (const int*)d_in[1];
    const float* ea = (const float*)d_in[2];
    const float* emb_w = (const float*)d_in[3];
    const float* emb_b = (const float*)d_in[4];
    const float* ew1 = (const float*)d_in[5];
    const float* eb1 = (const float*)d_in[6];
    const float* ew2 = (const float*)d_in[7];
    const float* eb2 = (const float*)d_in[8];
    const float* nw1 = (const float*)d_in[9];
    const float* nb1 = (const float*)d_in[10];
    const float* nw2 = (const float*)d_in[11];
    const float* nb2 = (const float*)d_in[12];
    const float* dw1 = (const float*)d_in[13];
    const float* db1 = (const float*)d_in[14];
    const float* dw2 = (const float*)d_in[15];
    const float* db2 = (const float*)d_in[16];
    const int* row = edges;
    const int* col = edges + N_EDGES;

    const size_t NH = (size_t)N_NODES * HID;
    float* r0 = (float*)d_ws;        // h (updated in place by k_node)
    float* r1 = r0 + NH;             // A
    float* r2 = r1 + NH;             // B
    float* r3 = r2 + NH;             // agg
    int* deg = (int*)(r3 + NH);
    int* off = deg + N_NODES;
    int* row_s = off + N_NODES;
    int* col_s = row_s + N_EDGES;
    float* ea_s = (float*)(col_s + N_EDGES);
    _Float16* W2p = (_Float16*)(ea_s + N_EDGES);
    _Float16* WpA  = W2p  + (size_t)4 * 16384;
    _Float16* WpB  = WpA  + (size_t)4 * 32768;
    _Float16* WpN1 = WpB  + (size_t)4 * 32768;
    _Float16* WpN2 = WpN1 + (size_t)4 * 65536;
    _Float16* WpD1 = WpN2 + (size_t)4 * 32768;

    // one-time: counting sort by row + weight pre-packs
    hipMemsetAsync(deg, 0, N_NODES * sizeof(int), stream);
    k_hist<<<(N_EDGES + 255) / 256, 256, 0, stream>>>(row, deg);
    k_scan<<<1, 1024, 0, stream>>>(deg, off);
    k_scatter<<<(N_EDGES + 255) / 256, 256, 0, stream>>>(row, col, ea, off, row_s, col_s, ea_s);
    k_packW2<<<N_LAYERS, 256, 0, stream>>>(ew2, W2p);
    k_packAll<<<17, 256, 0, stream>>>(ew1, nw1, nw2, dw1, WpA, WpB, WpN1, WpN2, WpD1);

    k_embed<<<(N_NODES * HID + 255) / 256, 256, 0, stream>>>(nodes, emb_w, emb_b, r0);

    const int g64 = (N_NODES + 63) / 64;      // 782
    const int g128 = (N_NODES + 127) / 128;   // 391

    // A0/B0 from h0
    k_gemm3<<<g64, 512, 0, stream>>>(r0, nullptr,
                                     WpA, eb1, r1,
                                     WpB, nullptr, r2,
                                     N_NODES, 8, 0);

    for (int l = 0; l < N_LAYERS; ++l) {
        hipMemsetAsync(r3, 0, NH * sizeof(float), stream);
        k_edge9<<<512, 512, 0, stream>>>(r1, r2,
                                         ew1 + (size_t)l * 257 * 128 + 256 * 128,
                                         eb2 + l * 128,
                                         W2p + (size_t)l * 16384,
                                         row_s, col_s, ea_s, r3);
        if (l < N_LAYERS - 1) {
            k_node<<<g128, 512, 0, stream>>>(r0, r3,
                                             WpN1 + (size_t)l * 65536, nb1 + l * 128,
                                             WpN2 + (size_t)l * 32768, nb2 + l * 128,
                                             WpA + (size_t)(l + 1) * 32768, eb1 + (l + 1) * 128,
                                             WpB + (size_t)(l + 1) * 32768,
                                             r1, r2,
                                             nullptr, nullptr, nullptr, nullptr, nullptr,
                                             N_NODES, 0);
        } else {
            k_node<<<g128, 512, 0, stream>>>(r0, r3,
                                             WpN1 + (size_t)l * 65536, nb1 + l * 128,
                                             WpN2 + (size_t)l * 32768, nb2 + l * 128,
                                             nullptr, nullptr, nullptr,
                                             nullptr, nullptr,
                                             WpD1, db1, dw2, db2,
                                             (float*)d_out, N_NODES, 1);
        }
    }
}

// Round 12
// 923.124 us; speedup vs baseline: 1.0980x; 1.0980x over previous
//
#include <hip/hip_runtime.h>

#define N_NODES 50000
#define N_EDGES 640000
#define HID 128
#define N_LAYERS 4
#define TILE_E 128

typedef _Float16 f16x8 __attribute__((ext_vector_type(8)));
typedef float f32x16 __attribute__((ext_vector_type(16)));

__device__ __forceinline__ float silu_f(float x) {
    return x * __builtin_amdgcn_rcpf(1.0f + __expf(-x));
}

__device__ __forceinline__ f32x16 zero16() {
    f32x16 z;
#pragma unroll
    for (int i = 0; i < 16; ++i) z[i] = 0.f;
    return z;
}

// h[i,c] = sum_k nodes[i,k]*emb_w[k,c] + emb_b[c]
__global__ void k_embed(const float* __restrict__ nodes, const float* __restrict__ ew,
                        const float* __restrict__ eb, float* __restrict__ h) {
    int idx = blockIdx.x * 256 + threadIdx.x;
    if (idx >= N_NODES * HID) return;
    int i = idx >> 7, c = idx & 127;
    float n0 = nodes[i * 3 + 0], n1 = nodes[i * 3 + 1], n2 = nodes[i * 3 + 2];
    h[idx] = n0 * ew[c] + n1 * ew[HID + c] + n2 * ew[2 * HID + c] + eb[c];
}

// ---- counting sort of edges by row ----
__global__ void k_hist(const int* __restrict__ row, int* __restrict__ deg) {
    int e = blockIdx.x * 256 + threadIdx.x;
    if (e < N_EDGES) atomicAdd(&deg[row[e]], 1);
}

__global__ __launch_bounds__(1024) void k_scan(const int* __restrict__ deg, int* __restrict__ off) {
    __shared__ int partial[1024];
    const int t = threadIdx.x;
    const int chunk = (N_NODES + 1023) / 1024;
    const int base = t * chunk;
    int s = 0;
    for (int i = 0; i < chunk; ++i) {
        int idx = base + i;
        if (idx < N_NODES) s += deg[idx];
    }
    partial[t] = s;
    __syncthreads();
    for (int o = 1; o < 1024; o <<= 1) {
        int v = (t >= o) ? partial[t - o] : 0;
        __syncthreads();
        partial[t] += v;
        __syncthreads();
    }
    int run = (t == 0) ? 0 : partial[t - 1];
    for (int i = 0; i < chunk; ++i) {
        int idx = base + i;
        if (idx < N_NODES) {
            off[idx] = run;
            run += deg[idx];
        }
    }
}

__global__ void k_scatter(const int* __restrict__ row, const int* __restrict__ col,
                          const float* __restrict__ ea, int* __restrict__ off,
                          int* __restrict__ row_s, int* __restrict__ col_s,
                          float* __restrict__ ea_s) {
    int e = blockIdx.x * 256 + threadIdx.x;
    if (e >= N_EDGES) return;
    int r = row[e];
    int pos = atomicAdd(&off[r], 1);
    row_s[pos] = r;
    col_s[pos] = col[e];
    ea_s[pos] = ea[e];
}

// Pack W2[l] (128x128) into single-f16 B-frags for the edge kernel.
__global__ __launch_bounds__(256) void k_packW2(const float* __restrict__ W2all,
                                                _Float16* __restrict__ W2p) {
    const int layer = blockIdx.x;
    const float* W2 = W2all + (size_t)layer * 128 * 128;
    _Float16* out = W2p + (size_t)layer * 128 * 128;
    const int t = threadIdx.x;
    for (int fl = t; fl < 2048; fl += 256) {
        int blk = fl >> 6, lane = fl & 63;
        int cb = blk >> 3, kb = blk & 7;
        int colg = cb * 32 + (lane & 31);
        int kbase = kb * 16 + (lane >> 5) * 8;
        f16x8 v;
#pragma unroll
        for (int j = 0; j < 8; ++j)
            v[j] = (_Float16)W2[(size_t)(kbase + j) * 128 + colg];
        *(f16x8*)&out[(size_t)fl * 8] = v;
    }
}

// Pack node-MLP / decoder weights into hi/lo split-f16 B-frags.
__global__ __launch_bounds__(256) void k_packAll(
    const float* __restrict__ ew1, const float* __restrict__ nw1,
    const float* __restrict__ nw2, const float* __restrict__ dw1,
    _Float16* __restrict__ WpA, _Float16* __restrict__ WpB,
    _Float16* __restrict__ WpN1, _Float16* __restrict__ WpN2,
    _Float16* __restrict__ WpD1) {
    const int b = blockIdx.x;
    const float* W; _Float16* dst; int K16;
    if (b < 4)       { W = ew1 + (size_t)b * 257 * 128;              dst = WpA  + (size_t)b * 32768; K16 = 8; }
    else if (b < 8)  { int l = b - 4;  W = ew1 + (size_t)l * 257 * 128 + 128 * 128; dst = WpB + (size_t)l * 32768; K16 = 8; }
    else if (b < 12) { int l = b - 8;  W = nw1 + (size_t)l * 256 * 128; dst = WpN1 + (size_t)l * 65536; K16 = 16; }
    else if (b < 16) { int l = b - 12; W = nw2 + (size_t)l * 128 * 128; dst = WpN2 + (size_t)l * 32768; K16 = 8; }
    else             { W = dw1; dst = WpD1; K16 = 8; }
    for (int fl = threadIdx.x; fl < K16 * 256; fl += 256) {
        int lane = fl & 63, cb = (fl >> 6) & 3, ks = fl >> 8;
        int col = cb * 32 + (lane & 31);
        int kb = ks * 16 + (lane >> 5) * 8;
        f16x8 h8, l8;
#pragma unroll
        for (int j = 0; j < 8; ++j) {
            float wv = W[(size_t)(kb + j) * 128 + col];
            _Float16 hh = (_Float16)wv;
            h8[j] = hh;
            l8[j] = (_Float16)((wv - (float)hh) * 2048.0f);
        }
        *(f16x8*)&dst[((size_t)(0 * K16 + ks) * 4 + cb) * 512 + lane * 8] = h8;
        *(f16x8*)&dst[((size_t)(1 * K16 + ks) * 4 + cb) * 512 + lane * 8] = l8;
    }
}

__device__ __forceinline__ void split8(const float* xv, f16x8& xh, f16x8& xl) {
#pragma unroll
    for (int q = 0; q < 8; ++q) {
        _Float16 hh = (_Float16)xv[q];
        xh[q] = hh;
        xl[q] = (_Float16)((xv[q] - (float)hh) * 2048.0f);
    }
}

// Split-f16 MFMA GEMM (initial A/B dual from h0).
__global__ __launch_bounds__(512) void k_gemm3(
    const float* __restrict__ X1, const float* __restrict__ X2,
    const _Float16* __restrict__ Wp0, const float* __restrict__ bias0, float* __restrict__ out0,
    const _Float16* __restrict__ Wp1, const float* __restrict__ bias1, float* __restrict__ out1,
    int M, int K16, int do_silu) {
    const int t = threadIdx.x, w = t >> 6, l = t & 63;
    const int lane31 = l & 31, hi = l >> 5;
    const bool dual = (Wp1 != nullptr);
    int rb, cb0, sel;
    if (dual) { rb = w & 1; sel = w >> 2; cb0 = ((w >> 1) & 1) * 2; }
    else      { rb = w & 3; sel = 0;      cb0 = (w >> 2) * 2; }
    const int mtile = dual ? 64 : 128;
    const int m0 = blockIdx.x * mtile;
    const _Float16* Wp = sel ? Wp1 : Wp0;
    const float* bias = sel ? bias1 : bias0;
    float* out = sel ? out1 : out0;

    int rowg = m0 + rb * 32 + lane31;
    if (rowg >= M) rowg = M - 1;
    const int koff = hi * 8;

    f32x16 aH0 = zero16(), aH1 = zero16(), aL0 = zero16(), aL1 = zero16();
    const f16x8* Wv = (const f16x8*)Wp;
#pragma unroll 4
    for (int ks = 0; ks < K16; ++ks) {
        const float* Xp = (X2 != nullptr && ks >= 8) ? X2 : X1;
        const float* px = &Xp[(size_t)rowg * 128 + (ks & 7) * 16 + koff];
        float xv[8];
        *(float4*)&xv[0] = *(const float4*)px;
        *(float4*)&xv[4] = *(const float4*)(px + 4);
        f16x8 xh, xl;
        split8(xv, xh, xl);
        f16x8 bh0 = Wv[((size_t)ks * 4 + cb0) * 64 + l];
        f16x8 bh1 = Wv[((size_t)ks * 4 + cb0 + 1) * 64 + l];
        f16x8 bl0 = Wv[((size_t)(K16 + ks) * 4 + cb0) * 64 + l];
        f16x8 bl1 = Wv[((size_t)(K16 + ks) * 4 + cb0 + 1) * 64 + l];
        aH0 = __builtin_amdgcn_mfma_f32_32x32x16_f16(xh, bh0, aH0, 0, 0, 0);
        aH1 = __builtin_amdgcn_mfma_f32_32x32x16_f16(xh, bh1, aH1, 0, 0, 0);
        aL0 = __builtin_amdgcn_mfma_f32_32x32x16_f16(xh, bl0, aL0, 0, 0, 0);
        aL0 = __builtin_amdgcn_mfma_f32_32x32x16_f16(xl, bh0, aL0, 0, 0, 0);
        aL1 = __builtin_amdgcn_mfma_f32_32x32x16_f16(xh, bl1, aL1, 0, 0, 0);
        aL1 = __builtin_amdgcn_mfma_f32_32x32x16_f16(xl, bh1, aL1, 0, 0, 0);
    }
    const float inv = 1.0f / 2048.0f;
#pragma unroll
    for (int c = 0; c < 2; ++c) {
        int col = (cb0 + c) * 32 + lane31;
        float bv = bias ? bias[col] : 0.f;
        const f32x16& aH = c ? aH1 : aH0;
        const f32x16& aL = c ? aL1 : aL0;
#pragma unroll
        for (int r = 0; r < 16; ++r) {
            int gr = m0 + rb * 32 + (r & 3) + 8 * (r >> 2) + 4 * hi;
            if (gr < M) {
                float v = aH[r] + aL[r] * inv + bv;
                out[(size_t)gr * 128 + col] = do_silu ? silu_f(v) : v;
            }
        }
    }
}

// Fused per-layer node kernel: u=silu([h,agg]@nw1+b) -> h'=u@nw2+b (in-place
// over h) -> next layer's A/B dual GEMM, OR (final) decoder to out[N,3].
// Non-final mode also ZEROES agg (for the next layer's edge pass) right after
// stage N1's reads complete — replaces the per-layer hipMemsetAsync.
__global__ __launch_bounds__(512) void k_node(
    float* __restrict__ h, float* __restrict__ agg,
    const _Float16* __restrict__ Wn1, const float* __restrict__ nb1,
    const _Float16* __restrict__ Wn2, const float* __restrict__ nb2,
    const _Float16* __restrict__ WA, const float* __restrict__ ebA,
    const _Float16* __restrict__ WB,
    float* __restrict__ outA, float* __restrict__ outB,
    const _Float16* __restrict__ WD, const float* __restrict__ db1,
    const float* __restrict__ dw2, const float* __restrict__ db2,
    float* __restrict__ dec_out, int M, int final_mode) {
    __shared__ float u_lds[128 * 133];
    __shared__ float w2l[384];
    const int t = threadIdx.x, w = t >> 6, l = t & 63;
    const int lane31 = l & 31, hi = l >> 5;
    const int rb = w & 3, cb0 = (w >> 2) * 2;
    const int m0 = blockIdx.x * 128;
    const int koff = hi * 8;
    const float inv = 1.0f / 2048.0f;

    if (final_mode && t < 384) w2l[t] = dw2[t];

    int rowg = m0 + rb * 32 + lane31;
    if (rowg >= M) rowg = M - 1;

    // ---- stage N1: u = silu([h, agg] @ nw1 + nb1) -> u_lds ----
    {
        f32x16 aH0 = zero16(), aH1 = zero16(), aL0 = zero16(), aL1 = zero16();
        const f16x8* Wv = (const f16x8*)Wn1;
#pragma unroll 4
        for (int ks = 0; ks < 16; ++ks) {
            const float* Xp = (ks >= 8) ? agg : h;
            const float* px = &Xp[(size_t)rowg * 128 + (ks & 7) * 16 + koff];
            float xv[8];
            *(float4*)&xv[0] = *(const float4*)px;
            *(float4*)&xv[4] = *(const float4*)(px + 4);
            f16x8 xh, xl;
            split8(xv, xh, xl);
            f16x8 bh0 = Wv[((size_t)ks * 4 + cb0) * 64 + l];
            f16x8 bh1 = Wv[((size_t)ks * 4 + cb0 + 1) * 64 + l];
            f16x8 bl0 = Wv[((size_t)(16 + ks) * 4 + cb0) * 64 + l];
            f16x8 bl1 = Wv[((size_t)(16 + ks) * 4 + cb0 + 1) * 64 + l];
            aH0 = __builtin_amdgcn_mfma_f32_32x32x16_f16(xh, bh0, aH0, 0, 0, 0);
            aH1 = __builtin_amdgcn_mfma_f32_32x32x16_f16(xh, bh1, aH1, 0, 0, 0);
            aL0 = __builtin_amdgcn_mfma_f32_32x32x16_f16(xh, bl0, aL0, 0, 0, 0);
            aL0 = __builtin_amdgcn_mfma_f32_32x32x16_f16(xl, bh0, aL0, 0, 0, 0);
            aL1 = __builtin_amdgcn_mfma_f32_32x32x16_f16(xh, bl1, aL1, 0, 0, 0);
            aL1 = __builtin_amdgcn_mfma_f32_32x32x16_f16(xl, bh1, aL1, 0, 0, 0);
        }
#pragma unroll
        for (int c = 0; c < 2; ++c) {
            int col = (cb0 + c) * 32 + lane31;
            float bv = nb1[col];
            const f32x16& aH = c ? aH1 : aH0;
            const f32x16& aL = c ? aL1 : aL0;
#pragma unroll
            for (int r = 0; r < 16; ++r) {
                int lr = rb * 32 + (r & 3) + 8 * (r >> 2) + 4 * hi;
                u_lds[lr * 133 + col] = silu_f(aH[r] + aL[r] * inv + bv);
            }
        }
    }
    __syncthreads();   // all agg reads (stage N1) complete block-wide

    // zero this block's agg rows for the next layer (overlaps stage N2)
    if (!final_mode) {
        // 128 rows x 128 cols = 16384 floats; 512 threads x 8 float4
        float4 z4 = make_float4(0.f, 0.f, 0.f, 0.f);
#pragma unroll
        for (int i = 0; i < 8; ++i) {
            int fi = (t + i * 512) * 4;        // float index 0..16383
            int lr = fi >> 7;
            int gr = m0 + lr;
            if (gr < M) *(float4*)&agg[(size_t)gr * 128 + (fi & 127)] = z4;
        }
    }

    // ---- stage N2: h' = u @ nw2 + nb2 -> u_lds (+ global h if !final) ----
    {
        f32x16 aH0 = zero16(), aH1 = zero16(), aL0 = zero16(), aL1 = zero16();
        const f16x8* Wv = (const f16x8*)Wn2;
#pragma unroll
        for (int ks = 0; ks < 8; ++ks) {
            float xv[8];
            const int base = (rb * 32 + lane31) * 133 + ks * 16 + koff;
#pragma unroll
            for (int q = 0; q < 8; ++q) xv[q] = u_lds[base + q];
            f16x8 xh, xl;
            split8(xv, xh, xl);
            f16x8 bh0 = Wv[((size_t)ks * 4 + cb0) * 64 + l];
            f16x8 bh1 = Wv[((size_t)ks * 4 + cb0 + 1) * 64 + l];
            f16x8 bl0 = Wv[((size_t)(8 + ks) * 4 + cb0) * 64 + l];
            f16x8 bl1 = Wv[((size_t)(8 + ks) * 4 + cb0 + 1) * 64 + l];
            aH0 = __builtin_amdgcn_mfma_f32_32x32x16_f16(xh, bh0, aH0, 0, 0, 0);
            aH1 = __builtin_amdgcn_mfma_f32_32x32x16_f16(xh, bh1, aH1, 0, 0, 0);
            aL0 = __builtin_amdgcn_mfma_f32_32x32x16_f16(xh, bl0, aL0, 0, 0, 0);
            aL0 = __builtin_amdgcn_mfma_f32_32x32x16_f16(xl, bh0, aL0, 0, 0, 0);
            aL1 = __builtin_amdgcn_mfma_f32_32x32x16_f16(xh, bl1, aL1, 0, 0, 0);
            aL1 = __builtin_amdgcn_mfma_f32_32x32x16_f16(xl, bh1, aL1, 0, 0, 0);
        }
        __syncthreads();   // all u_lds reads done before overwrite
#pragma unroll
        for (int c = 0; c < 2; ++c) {
            int col = (cb0 + c) * 32 + lane31;
            float bv = nb2[col];
            const f32x16& aH = c ? aH1 : aH0;
            const f32x16& aL = c ? aL1 : aL0;
#pragma unroll
            for (int r = 0; r < 16; ++r) {
                int lr = rb * 32 + (r & 3) + 8 * (r >> 2) + 4 * hi;
                float v = aH[r] + aL[r] * inv + bv;
                u_lds[lr * 133 + col] = v;
                int gr = m0 + lr;
                if (!final_mode && gr < M) h[(size_t)gr * 128 + col] = v;
            }
        }
    }
    __syncthreads();

    if (!final_mode) {
        // ---- stage 3: A = h'@W1a + eb1, B = h'@W1b (next layer) ----
#pragma unroll
        for (int pass = 0; pass < 2; ++pass) {
            const int sel = w >> 2, w2 = w & 3;
            const int cbp = w2 >> 1, cb0p = (cbp) * 2;
            const int rb3 = (w2 & 1) * 2 + pass;
            const _Float16* Wp = sel ? WB : WA;
            float* op = sel ? outB : outA;
            f32x16 aH0 = zero16(), aH1 = zero16(), aL0 = zero16(), aL1 = zero16();
            const f16x8* Wv = (const f16x8*)Wp;
#pragma unroll
            for (int ks = 0; ks < 8; ++ks) {
                float xv[8];
                const int base = (rb3 * 32 + lane31) * 133 + ks * 16 + koff;
#pragma unroll
                for (int q = 0; q < 8; ++q) xv[q] = u_lds[base + q];
                f16x8 xh, xl;
                split8(xv, xh, xl);
                f16x8 bh0 = Wv[((size_t)ks * 4 + cb0p) * 64 + l];
                f16x8 bh1 = Wv[((size_t)ks * 4 + cb0p + 1) * 64 + l];
                f16x8 bl0 = Wv[((size_t)(8 + ks) * 4 + cb0p) * 64 + l];
                f16x8 bl1 = Wv[((size_t)(8 + ks) * 4 + cb0p + 1) * 64 + l];
                aH0 = __builtin_amdgcn_mfma_f32_32x32x16_f16(xh, bh0, aH0, 0, 0, 0);
                aH1 = __builtin_amdgcn_mfma_f32_32x32x16_f16(xh, bh1, aH1, 0, 0, 0);
                aL0 = __builtin_amdgcn_mfma_f32_32x32x16_f16(xh, bl0, aL0, 0, 0, 0);
                aL0 = __builtin_amdgcn_mfma_f32_32x32x16_f16(xl, bh0, aL0, 0, 0, 0);
                aL1 = __builtin_amdgcn_mfma_f32_32x32x16_f16(xh, bl1, aL1, 0, 0, 0);
                aL1 = __builtin_amdgcn_mfma_f32_32x32x16_f16(xl, bh1, aL1, 0, 0, 0);
            }
#pragma unroll
            for (int c = 0; c < 2; ++c) {
                int col = (cb0p + c) * 32 + lane31;
                float bv = sel ? 0.f : ebA[col];
                const f32x16& aH = c ? aH1 : aH0;
                const f32x16& aL = c ? aL1 : aL0;
#pragma unroll
                for (int r = 0; r < 16; ++r) {
                    int gr = m0 + rb3 * 32 + (r & 3) + 8 * (r >> 2) + 4 * hi;
                    if (gr < M) op[(size_t)gr * 128 + col] = aH[r] + aL[r] * inv + bv;
                }
            }
        }
    } else {
        // ---- decoder: u2 = silu(h'@dw1+db1) -> u_lds; out = u2@dw2+db2 ----
        f32x16 aH0 = zero16(), aH1 = zero16(), aL0 = zero16(), aL1 = zero16();
        const f16x8* Wv = (const f16x8*)WD;
#pragma unroll
        for (int ks = 0; ks < 8; ++ks) {
            float xv[8];
            const int base = (rb * 32 + lane31) * 133 + ks * 16 + koff;
#pragma unroll
            for (int q = 0; q < 8; ++q) xv[q] = u_lds[base + q];
            f16x8 xh, xl;
            split8(xv, xh, xl);
            f16x8 bh0 = Wv[((size_t)ks * 4 + cb0) * 64 + l];
            f16x8 bh1 = Wv[((size_t)ks * 4 + cb0 + 1) * 64 + l];
            f16x8 bl0 = Wv[((size_t)(8 + ks) * 4 + cb0) * 64 + l];
            f16x8 bl1 = Wv[((size_t)(8 + ks) * 4 + cb0 + 1) * 64 + l];
            aH0 = __builtin_amdgcn_mfma_f32_32x32x16_f16(xh, bh0, aH0, 0, 0, 0);
            aH1 = __builtin_amdgcn_mfma_f32_32x32x16_f16(xh, bh1, aH1, 0, 0, 0);
            aL0 = __builtin_amdgcn_mfma_f32_32x32x16_f16(xh, bl0, aL0, 0, 0, 0);
            aL0 = __builtin_amdgcn_mfma_f32_32x32x16_f16(xl, bh0, aL0, 0, 0, 0);
            aL1 = __builtin_amdgcn_mfma_f32_32x32x16_f16(xh, bl1, aL1, 0, 0, 0);
            aL1 = __builtin_amdgcn_mfma_f32_32x32x16_f16(xl, bh1, aL1, 0, 0, 0);
        }
        __syncthreads();
#pragma unroll
        for (int c = 0; c < 2; ++c) {
            int col = (cb0 + c) * 32 + lane31;
            float bv = db1[col];
            const f32x16& aH = c ? aH1 : aH0;
            const f32x16& aL = c ? aL1 : aL0;
#pragma unroll
            for (int r = 0; r < 16; ++r) {
                int lr = rb * 32 + (r & 3) + 8 * (r >> 2) + 4 * hi;
                u_lds[lr * 133 + col] = silu_f(aH[r] + aL[r] * inv + bv);
            }
        }
        __syncthreads();
        if (t < 384) {
            int rowl = t & 127, j = t >> 7;
            int gm = m0 + rowl;
            if (gm < M) {
                float s = db2[j];
                for (int c = 0; c < 128; ++c)
                    s += u_lds[rowl * 133 + c] * w2l[c * 3 + j];
                dec_out[(size_t)gm * 3 + j] = s;
            }
        }
    }
}

// Edge kernel v4b = proven edge4 + w1last hoisted out of the tile loop
// (tile-invariant loads; +32 VGPR, still <=128 so 2-block/CU occupancy holds).
__global__ __launch_bounds__(512, 4) void k_edge4b(
    const float* __restrict__ A, const float* __restrict__ Bm,
    const float* __restrict__ w1last, const float* __restrict__ b2,
    const _Float16* __restrict__ W2p, const int* __restrict__ row_s,
    const int* __restrict__ col_s, const float* __restrict__ ea_s,
    float* __restrict__ agg) {
    __shared__ __align__(16) _Float16 W2s[16384];
    __shared__ __align__(16) _Float16 m1f[TILE_E * 136];  // frags, then mo[128][136]
    __shared__ int rows_sh[TILE_E];
    __shared__ int segs_sh[TILE_E + 2];
    __shared__ unsigned long long masks_sh[2];

    const int t = threadIdx.x;
    const int w = t >> 6, l = t & 63;
    const int lane31 = l & 31, hi = l >> 5;

    for (int i = t; i < 2048; i += 512)
        ((float4*)W2s)[i] = ((const float4*)W2p)[i];

    const int e_mine = (w >> 1) * 32 + lane31;
    const int kbase0 = (w & 1) * 64 + hi * 8;

    const int rb_g = w & 3;
    const int cb0 = (w >> 2) * 2, cb1 = cb0 + 1;
    const float b20 = b2[cb0 * 32 + lane31];
    const float b21 = b2[cb1 * 32 + lane31];

    // hoisted: w1last chunk for this thread (tile-invariant)
    float wl[32];
#pragma unroll
    for (int j = 0; j < 4; ++j) {
        int k0 = kbase0 + j * 16;
        *(float4*)&wl[j * 8] = *(const float4*)&w1last[k0];
        *(float4*)&wl[j * 8 + 4] = *(const float4*)&w1last[k0 + 4];
    }

    const f16x8* m1v = (const f16x8*)m1f;
    const f16x8* w2v = (const f16x8*)W2s;
    _Float16* mo = m1f;

    const int n_tiles = N_EDGES / TILE_E;  // 5000
    const int stride = gridDim.x;

    int r_pf = 0; float ea_pf = 0.f;
    float bpf[32];

    auto issue_pf = [&](int tile) {
        int eg = tile * TILE_E + e_mine;
        r_pf = row_s[eg];
        int c = col_s[eg];
        ea_pf = ea_s[eg];
        const float* Bp = Bm + (size_t)c * 128;
#pragma unroll
        for (int j = 0; j < 4; ++j) {
            int k0 = kbase0 + j * 16;
            *(float4*)&bpf[j * 8] = *(const float4*)&Bp[k0];
            *(float4*)&bpf[j * 8 + 4] = *(const float4*)&Bp[k0 + 4];
        }
    };

    int tile = blockIdx.x;
    if (tile < n_tiles) issue_pf(tile);

    for (; tile < n_tiles; tile += stride) {
        __syncthreads();  // prev phase4 done with mo; W2s staged (iter 0)

        // ---- phase 1: m1 = silu(A[row]+B[col]+ea*w1l) -> f16 A-frags ----
        {
            const int r = r_pf;
            const float eav = ea_pf;
            const float* Ap = A + (size_t)r * 128;
#pragma unroll
            for (int j = 0; j < 4; ++j) {
                int k0 = kbase0 + j * 16;
                float av[8];
                *(float4*)&av[0] = *(const float4*)&Ap[k0];
                *(float4*)&av[4] = *(const float4*)&Ap[k0 + 4];
                f16x8 o;
#pragma unroll
                for (int q = 0; q < 8; ++q)
                    o[q] = (_Float16)silu_f(av[q] + bpf[j * 8 + q] + eav * wl[j * 8 + q]);
                *(f16x8*)&m1f[(w * 4 + j) * 512 + l * 8] = o;
            }
            if ((w & 1) == 0 && hi == 0) rows_sh[e_mine] = r;
        }
        __syncthreads();  // frags + rows_sh ready

        if (t < 128) {
            bool flag = (t == 0) || (rows_sh[t] != rows_sh[t - 1]);
            unsigned long long m = __ballot(flag);
            if ((t & 63) == 0) masks_sh[t >> 6] = m;
        }

        // prefetch next tile's B + indices (hides under MFMA/epilogue)
        int nt = tile + stride;
        if (nt < n_tiles) issue_pf(nt);

        // ---- phase 2: MFMA ----
        f32x16 acc0 = zero16(), acc1 = zero16();
#pragma unroll
        for (int kb = 0; kb < 8; ++kb) {
            f16x8 a = m1v[(rb_g * 8 + kb) * 64 + l];
            acc0 = __builtin_amdgcn_mfma_f32_32x32x16_f16(a, w2v[(cb0 * 8 + kb) * 64 + l], acc0, 0, 0, 0);
            acc1 = __builtin_amdgcn_mfma_f32_32x32x16_f16(a, w2v[(cb1 * 8 + kb) * 64 + l], acc1, 0, 0, 0);
        }
        __syncthreads();  // frags consumed; masks visible

        const unsigned long long m0 = masks_sh[0], m1m = masks_sh[1];
        const int ns = __popcll(m0) + __popcll(m1m);
        if (t < 128) {
            bool bit = (t < 64) ? ((m0 >> t) & 1ull) : ((m1m >> (t - 64)) & 1ull);
            if (bit) {
                int idx = (t < 64) ? __popcll(m0 & ((1ull << t) - 1))
                                   : __popcll(m0) + __popcll(m1m & ((1ull << (t - 64)) - 1));
                segs_sh[idx] = t;
            }
        }
        if (t == 0) segs_sh[ns] = TILE_E;

        // ---- phase 3: silu epilogue -> mo[128][136] f16 ----
#pragma unroll
        for (int r = 0; r < 16; ++r) {
            int rowi = (r & 3) + 8 * (r >> 2) + 4 * hi;
            int erow = rb_g * 32 + rowi;
            mo[erow * 136 + cb0 * 32 + lane31] = (_Float16)silu_f(acc0[r] + b20);
            mo[erow * 136 + cb1 * 32 + lane31] = (_Float16)silu_f(acc1[r] + b21);
        }
        __syncthreads();  // mo + segs ready

        // ---- phase 4: per-segment column sums + atomics ----
        {
            const int c = t & 127, g = t >> 7;
            for (int s = g; s < ns; s += 4) {
                int st = segs_sh[s], en = segs_sh[s + 1];
                float sum = 0.f;
                for (int q = st; q < en; ++q) sum += (float)mo[q * 136 + c];
                atomicAdd(&agg[(size_t)rows_sh[st] * 128 + c], sum);
            }
        }
    }
}

extern "C" void kernel_launch(void* const* d_in, const int* in_sizes, int n_in,
                              void* d_out, int out_size, void* d_ws, size_t ws_size,
                              hipStream_t stream) {
    const float* nodes = (const float*)d_in[0];
    const int* edges = (const int*)d_in[1];
    const float* ea = (const float*)d_in[2];
    const float* emb_w = (const float*)d_in[3];
    const float* emb_b = (const float*)d_in[4];
    const float* ew1 = (const float*)d_in[5];
    const float* eb1 = (const float*)d_in[6];
    const float* ew2 = (const float*)d_in[7];
    const float* eb2 = (const float*)d_in[8];
    const float* nw1 = (const float*)d_in[9];
    const float* nb1 = (const float*)d_in[10];
    const float* nw2 = (const float*)d_in[11];
    const float* nb2 = (const float*)d_in[12];
    const float* dw1 = (const float*)d_in[13];
    const float* db1 = (const float*)d_in[14];
    const float* dw2 = (const float*)d_in[15];
    const float* db2 = (const float*)d_in[16];
    const int* row = edges;
    const int* col = edges + N_EDGES;

    const size_t NH = (size_t)N_NODES * HID;
    float* r0 = (float*)d_ws;        // h (updated in place by k_node)
    float* r1 = r0 + NH;             // A
    float* r2 = r1 + NH;             // B
    float* r3 = r2 + NH;             // agg
    int* deg = (int*)(r3 + NH);
    int* off = deg + N_NODES;
    int* row_s = off + N_NODES;
    int* col_s = row_s + N_EDGES;
    float* ea_s = (float*)(col_s + N_EDGES);
    _Float16* W2p = (_Float16*)(ea_s + N_EDGES);
    _Float16* WpA  = W2p  + (size_t)4 * 16384;
    _Float16* WpB  = WpA  + (size_t)4 * 32768;
    _Float16* WpN1 = WpB  + (size_t)4 * 32768;
    _Float16* WpN2 = WpN1 + (size_t)4 * 65536;
    _Float16* WpD1 = WpN2 + (size_t)4 * 32768;

    // one-time: counting sort by row + weight pre-packs
    hipMemsetAsync(deg, 0, N_NODES * sizeof(int), stream);
    k_hist<<<(N_EDGES + 255) / 256, 256, 0, stream>>>(row, deg);
    k_scan<<<1, 1024, 0, stream>>>(deg, off);
    k_scatter<<<(N_EDGES + 255) / 256, 256, 0, stream>>>(row, col, ea, off, row_s, col_s, ea_s);
    k_packW2<<<N_LAYERS, 256, 0, stream>>>(ew2, W2p);
    k_packAll<<<17, 256, 0, stream>>>(ew1, nw1, nw2, dw1, WpA, WpB, WpN1, WpN2, WpD1);

    k_embed<<<(N_NODES * HID + 255) / 256, 256, 0, stream>>>(nodes, emb_w, emb_b, r0);

    const int g64 = (N_NODES + 63) / 64;      // 782
    const int g128 = (N_NODES + 127) / 128;   // 391

    // A0/B0 from h0
    k_gemm3<<<g64, 512, 0, stream>>>(r0, nullptr,
                                     WpA, eb1, r1,
                                     WpB, nullptr, r2,
                                     N_NODES, 8, 0);

    // agg zero for layer 0 (later layers zeroed inside k_node)
    hipMemsetAsync(r3, 0, NH * sizeof(float), stream);

    for (int l = 0; l < N_LAYERS; ++l) {
        k_edge4b<<<512, 512, 0, stream>>>(r1, r2,
                                          ew1 + (size_t)l * 257 * 128 + 256 * 128,
                                          eb2 + l * 128,
                                          W2p + (size_t)l * 16384,
                                          row_s, col_s, ea_s, r3);
        if (l < N_LAYERS - 1) {
            k_node<<<g128, 512, 0, stream>>>(r0, r3,
                                             WpN1 + (size_t)l * 65536, nb1 + l * 128,
                                             WpN2 + (size_t)l * 32768, nb2 + l * 128,
                                             WpA + (size_t)(l + 1) * 32768, eb1 + (l + 1) * 128,
                                             WpB + (size_t)(l + 1) * 32768,
                                             r1, r2,
                                             nullptr, nullptr, nullptr, nullptr, nullptr,
                                             N_NODES, 0);
        } else {
            k_node<<<g128, 512, 0, stream>>>(r0, r3,
                                             WpN1 + (size_t)l * 65536, nb1 + l * 128,
                                             WpN2 + (size_t)l * 32768, nb2 + l * 128,
                                             nullptr, nullptr, nullptr,
                                             nullptr, nullptr,
                                             WpD1, db1, dw2, db2,
                                             (float*)d_out, N_NODES, 1);
        }
    }
}